// Round 1
// baseline (1933.847 us; speedup 1.0000x reference)
//
#include <hip/hip_runtime.h>

#define B_    1024
#define T_    256
#define LOCN  40001
#define E_    100
#define H_    100
#define NC    600   // [0,400): gates (i|f|g|o) preact, [400,500): t preact, [500,600): s preact

// ---------------------------------------------------------------------------
// Kernel 1: P_loc[LOC][600] = emb_loc @ [W_ih | W_xt | W_xs] + [b | b_t | b_s]
// PROWS=32: 32 FMAs amortize each W element load (was 16).
// ---------------------------------------------------------------------------
constexpr int PROWS = 32;
constexpr int PPAD  = 36;   // 36 dwords: 16B-aligned rows, non-pow2 stride

__global__ __launch_bounds__(320) void proj_loc_kernel(
    const float* __restrict__ emb_loc,
    const float* __restrict__ W_ih,   // [100][400]
    const float* __restrict__ W_xt,   // [100][100]
    const float* __restrict__ W_xs,   // [100][100]
    const float* __restrict__ b,      // [400]
    const float* __restrict__ b_t,    // [100]
    const float* __restrict__ b_s,    // [100]
    float* __restrict__ P)            // [LOC][600]
{
    __shared__ __attribute__((aligned(16))) float aT[E_][PPAD];  // transposed tile
    const int tid  = threadIdx.x;
    const int row0 = blockIdx.x * PROWS;

    for (int i = tid; i < PROWS * E_; i += 320) {
        int r = i / E_, k = i - r * E_;
        int rr = row0 + r;
        float v = 0.f;
        if (rr < LOCN) v = emb_loc[rr * E_ + k];
        aT[k][r] = v;
    }
    __syncthreads();
    if (tid >= 300) return;

    for (int cc = 0; cc < 2; ++cc) {
        const int c = tid + cc * 300;
        const float* wp; int stride; float bias;
        if (c < 400)      { wp = W_ih + c;         stride = 400; bias = b[c]; }
        else if (c < 500) { wp = W_xt + (c - 400); stride = 100; bias = b_t[c - 400]; }
        else              { wp = W_xs + (c - 500); stride = 100; bias = b_s[c - 500]; }

        float acc[PROWS];
        #pragma unroll
        for (int r = 0; r < PROWS; ++r) acc[r] = bias;

        for (int k = 0; k < E_; ++k) {
            float wv = wp[(size_t)k * stride];
            #pragma unroll
            for (int r = 0; r < PROWS; ++r) acc[r] += aT[k][r] * wv;
        }
        #pragma unroll
        for (int r = 0; r < PROWS; ++r) {
            int rr = row0 + r;
            if (rr < LOCN) P[(size_t)rr * NC + c] = acc[r];
        }
    }
}

// ---------------------------------------------------------------------------
// Kernel 2: P_t[92][100] = emb_t @ W_tt ; P_s[92][100] = emb_s @ W_ss
// ---------------------------------------------------------------------------
__global__ void proj_ts_kernel(
    const float* __restrict__ emb_t, const float* __restrict__ emb_s,
    const float* __restrict__ W_tt,  const float* __restrict__ W_ss,
    float* __restrict__ P_t, float* __restrict__ P_s)
{
    int idx = blockIdx.x * 256 + threadIdx.x;
    if (idx >= 2 * 92 * H_) return;
    int which = idx / (92 * H_);
    int rem   = idx - which * (92 * H_);
    int r = rem / H_, c = rem - r * H_;
    const float* e = which ? emb_s : emb_t;
    const float* W = which ? W_ss : W_tt;
    float acc = 0.f;
    #pragma unroll
    for (int k = 0; k < 12; ++k) acc += e[r * 12 + k] * W[k * H_ + c];
    (which ? P_s : P_t)[rem] = acc;
}

// ---------------------------------------------------------------------------
// Kernel 3: recurrence. 512 blocks x 448 threads, RB=2 batch rows/block,
// 2 blocks/CU. One raw barrier per step (no vmcnt drain).
//   tid<400, gate role : column n = (tid&3)*100 + (tid>>2)  (i,f,g,o of one
//                        h-index in 4 adjacent lanes -> shuffle epilogue)
//   tid<400, ts role   : channel ch = tid%200 of row tid/200, computed one
//                        step AHEAD into double-buffered tg/sg_lds
// All global loads issued >=1 step before use; stay in flight across barriers.
// ---------------------------------------------------------------------------
constexpr int RB = 2;
constexpr int NT = 448;

__global__ __launch_bounds__(NT, 4) void lstm_rec_kernel(
    const int* __restrict__ traj,
    const int* __restrict__ traj_len_p,
    const int* __restrict__ tu,      const int* __restrict__ tl,
    const int* __restrict__ tu_slot, const int* __restrict__ tl_slot,
    const int* __restrict__ su,      const int* __restrict__ sl,
    const int* __restrict__ su_slot, const int* __restrict__ sl_slot,
    const float* __restrict__ P,     // [LOC][600]
    const float* __restrict__ P_t,   // [92][100]
    const float* __restrict__ P_s,   // [92][100]
    const float* __restrict__ W_hh,  // [100][400]
    float* __restrict__ out)         // [B][100]
{
    __shared__ __attribute__((aligned(16))) float h_lds[2][RB][H_];
    __shared__ float tg_lds[2][RB][H_];
    __shared__ float sg_lds[2][RB][H_];

    const int tid = threadIdx.x;
    const int b0  = blockIdx.x * RB;
    const int tb0 = b0 * T_;
    const int tb1 = tb0 + T_;
    int steps = traj_len_p[0] + 1;
    if (steps > T_) steps = T_;
    steps = __builtin_amdgcn_readfirstlane(steps);

    // gate-role constants
    const int gi = tid & 3;          // 0=i 1=f 2=g 3=o
    const int q  = tid >> 2;         // h-index (tid<400 -> q<100)
    const int n  = gi * 100 + q;     // W_hh / P column

    // ts-role constants
    const int  tsr  = tid / 200;                 // batch row 0/1 (tid<400)
    const int  ch   = tid - tsr * 200;           // 0..199
    const bool is_t = ch < 100;
    const int  hx   = is_t ? ch : ch - 100;
    const int* up_a = is_t ? tu_slot : su_slot;
    const int* lo_a = is_t ? tl_slot : sl_slot;
    const int* ui_a = is_t ? tu : su;
    const int* li_a = is_t ? tl : sl;
    const float* Pq = is_t ? P_t : P_s;
    const int  tso  = (tsr == 1) ? tb1 : tb0;
    const int  gcol = 400 + ch;
    float* tsw = (is_t ? &tg_lds[0][0][0] : &sg_lds[0][0][0]) + tsr * H_ + hx;

    // W_hh column -> registers (persist across all steps)
    float w[H_];
    if (tid < 400) {
        #pragma unroll
        for (int k = 0; k < H_; ++k) w[k] = W_hh[k * 400 + n];
    }
    if (tid < RB * H_) ((float*)h_lds)[tid] = 0.f;   // h_lds[0] = 0

    float c0 = 0.f, c1 = 0.f;
    int lB0 = 0, lB1 = 0, lC0 = 0, lC1 = 0;          // loc[t+1], loc[t+2]
    int uA = 0, lsA = 0, uiA = 0, liA = 0; float gpA = 0.f;   // tsin set A
    int uB = 0, lsB = 0, uiB = 0, liB = 0; float gpB = 0.f;   // tsin set B
    float gA0 = 0.f, gA1 = 0.f, gB0 = 0.f, gB1 = 0.f;         // gate P rows

    if (tid < 400) {
        const int t1 = (steps > 1) ? 1 : 0;
        const int t2 = (steps > 2) ? 2 : steps - 1;
        const int lA0 = __builtin_amdgcn_readfirstlane(traj[tb0]);
        const int lA1 = __builtin_amdgcn_readfirstlane(traj[tb1]);
        lB0 = __builtin_amdgcn_readfirstlane(traj[tb0 + t1]);
        lB1 = __builtin_amdgcn_readfirstlane(traj[tb1 + t1]);
        lC0 = __builtin_amdgcn_readfirstlane(traj[tb0 + t2]);
        lC1 = __builtin_amdgcn_readfirstlane(traj[tb1 + t2]);
        // gate preact gather for t=0
        gA0 = P[(size_t)lA0 * NC + n];
        gA1 = P[(size_t)lA1 * NC + n];
        // tsg(0) computed directly
        {
            const int off0 = tso;
            const float fu = (float)up_a[off0], fl = (float)lo_a[off0];
            const int   iu = ui_a[off0],       il = li_a[off0];
            const float gp = P[(size_t)((tsr == 1) ? lA1 : lA0) * NC + gcol];
            const float iv = (fu * Pq[il * H_ + hx] + fl * Pq[iu * H_ + hx])
                             / fmaxf(fu + fl, 1.f);
            tsw[0] = 1.f / (1.f + expf(-(gp + iv)));
        }
        // tsin A = inputs for tsg(1): ints at t1, P-row via loc[t1]
        {
            const int off1 = tso + t1;
            uA = up_a[off1]; lsA = lo_a[off1]; uiA = ui_a[off1]; liA = li_a[off1];
            gpA = P[(size_t)((tsr == 1) ? lB1 : lB0) * NC + gcol];
        }
    }
    __syncthreads();

// One recurrence step. CUR is a compile-time buffer index; the A/B register
// sets alternate so prefetch destinations never overlap live values.
#define LSTM_STEP(tt, CUR, uC,lsC,uiC,liC,gpC,  uN,lsN,uiN,liN,gpN,  gC0,gC1, gN0,gN1)  \
  {                                                                                     \
    constexpr int CB = (CUR);                                                           \
    constexpr int NB = CB ^ 1;                                                          \
    if (tid < 400) {                                                                    \
      const int tD = ((tt) + 3 < steps) ? (tt) + 3 : steps - 1;                         \
      const int t2 = ((tt) + 2 < steps) ? (tt) + 2 : steps - 1;                         \
      const int nD0 = __builtin_amdgcn_readfirstlane(traj[tb0 + tD]);                   \
      const int nD1 = __builtin_amdgcn_readfirstlane(traj[tb1 + tD]);                   \
      /* prefetch gate P-rows for tt+1 (consumed next step) */                          \
      gN0 = P[(size_t)lB0 * NC + n];                                                    \
      gN1 = P[(size_t)lB1 * NC + n];                                                    \
      /* prefetch ts inputs for tsg(tt+2) (consumed next step) */                       \
      const int off2 = tso + t2;                                                        \
      uN  = up_a[off2]; lsN = lo_a[off2]; uiN = ui_a[off2]; liN = li_a[off2];           \
      gpN = P[(size_t)((tsr == 1) ? lC1 : lC0) * NC + gcol];                            \
      /* interp table loads for tsg(tt+1) (L2-resident, consumed below) */              \
      const float pql = Pq[(liC) * H_ + hx];                                            \
      const float pqu = Pq[(uiC) * H_ + hx];                                            \
      /* h @ W_hh */                                                                    \
      float acc0 = 0.f, acc1 = 0.f;                                                     \
      _Pragma("unroll")                                                                 \
      for (int k4 = 0; k4 < H_ / 4; ++k4) {                                             \
        const float4 h0 = *(const float4*)(&h_lds[CB][0][k4 * 4]);                      \
        const float4 h1 = *(const float4*)(&h_lds[CB][1][k4 * 4]);                      \
        acc0 += h0.x * w[k4*4+0]; acc0 += h0.y * w[k4*4+1];                             \
        acc0 += h0.z * w[k4*4+2]; acc0 += h0.w * w[k4*4+3];                             \
        acc1 += h1.x * w[k4*4+0]; acc1 += h1.y * w[k4*4+1];                             \
        acc1 += h1.z * w[k4*4+2]; acc1 += h1.w * w[k4*4+3];                             \
      }                                                                                 \
      /* activations */                                                                 \
      const bool isg = (gi == 2);                                                       \
      const float v0 = acc0 + gC0;                                                      \
      const float v1 = acc1 + gC1;                                                      \
      const float x0 = isg ? 2.f * v0 : v0;                                             \
      const float x1 = isg ? 2.f * v1 : v1;                                             \
      const float s0 = 1.f / (1.f + expf(-x0));                                         \
      const float s1 = 1.f / (1.f + expf(-x1));                                         \
      const float a0 = isg ? 2.f * s0 - 1.f : s0;                                       \
      const float a1 = isg ? 2.f * s1 - 1.f : s1;                                       \
      /* all-gather i,f,g,o within the 4-lane group */                                  \
      const float f0 = __shfl_xor(a0, 1);                                               \
      const float g0 = __shfl_xor(a0, 2);                                               \
      const float o0 = __shfl_xor(f0, 2);                                               \
      const float f1 = __shfl_xor(a1, 1);                                               \
      const float g1 = __shfl_xor(a1, 2);                                               \
      const float o1 = __shfl_xor(f1, 2);                                               \
      if (gi == 0) {    /* lane holds i; f0,g0,o0 = f,g,o */                            \
        const float ts0 = tg_lds[CB][0][q] * sg_lds[CB][0][q];                          \
        const float ts1 = tg_lds[CB][1][q] * sg_lds[CB][1][q];                          \
        c0 = f0 * c0 + a0 * ts0 * g0;                                                   \
        c1 = f1 * c1 + a1 * ts1 * g1;                                                   \
        h_lds[NB][0][q] = o0 * tanhf(c0);                                               \
        h_lds[NB][1][q] = o1 * tanhf(c1);                                               \
      }                                                                                 \
      /* t/s gate for tt+1 from prefetched inputs */                                    \
      {                                                                                 \
        const float fu = (float)(uC), fl = (float)(lsC);                                \
        const float iv = (fu * pql + fl * pqu) / fmaxf(fu + fl, 1.f);                   \
        tsw[NB * (RB * H_)] = 1.f / (1.f + expf(-((gpC) + iv)));                        \
      }                                                                                 \
      lB0 = lC0; lB1 = lC1; lC0 = nD0; lC1 = nD1;                                       \
    }                                                                                   \
    /* drain LDS only; global prefetches stay in flight across the barrier */           \
    asm volatile("s_waitcnt lgkmcnt(0)\n\ts_barrier" ::: "memory");                     \
  }

    int t = 0;
    for (; t + 1 < steps; t += 2) {
        LSTM_STEP(t,     0, uA,lsA,uiA,liA,gpA, uB,lsB,uiB,liB,gpB, gA0,gA1, gB0,gB1)
        LSTM_STEP(t + 1, 1, uB,lsB,uiB,liB,gpB, uA,lsA,uiA,liA,gpA, gB0,gB1, gA0,gA1)
    }
    if (t < steps) {
        LSTM_STEP(t, 0, uA,lsA,uiA,liA,gpA, uB,lsB,uiB,liB,gpB, gA0,gA1, gB0,gB1)
    }
#undef LSTM_STEP

    if (tid < RB * H_) {
        const int r  = tid / H_;
        const int qq = tid - r * H_;
        out[(b0 + r) * H_ + qq] = h_lds[steps & 1][r][qq];
    }
}

// ---------------------------------------------------------------------------
extern "C" void kernel_launch(void* const* d_in, const int* in_sizes, int n_in,
                              void* d_out, int out_size, void* d_ws, size_t ws_size,
                              hipStream_t stream) {
    const int*   traj     = (const int*)  d_in[0];
    // d_in[1] = lennew (unused by the reference)
    const int*   traj_len = (const int*)  d_in[2];
    const int*   tu       = (const int*)  d_in[3];
    const int*   tl       = (const int*)  d_in[4];
    const int*   tu_slot  = (const int*)  d_in[5];
    const int*   tl_slot  = (const int*)  d_in[6];
    const int*   su       = (const int*)  d_in[7];
    const int*   sl       = (const int*)  d_in[8];
    const int*   su_slot  = (const int*)  d_in[9];
    const int*   sl_slot  = (const int*)  d_in[10];
    const float* emb_loc  = (const float*)d_in[11];
    const float* emb_t    = (const float*)d_in[12];
    const float* emb_s    = (const float*)d_in[13];
    const float* W_ih     = (const float*)d_in[14];
    const float* W_hh     = (const float*)d_in[15];
    const float* b        = (const float*)d_in[16];
    const float* W_xt     = (const float*)d_in[17];
    const float* W_tt     = (const float*)d_in[18];
    const float* b_t      = (const float*)d_in[19];
    const float* W_xs     = (const float*)d_in[20];
    const float* W_ss     = (const float*)d_in[21];
    const float* b_s      = (const float*)d_in[22];

    float* P   = (float*)d_ws;              // 40001*600 floats (96.0 MB)
    float* P_t = P + (size_t)LOCN * NC;     // 9200 floats
    float* P_s = P_t + 92 * H_;             // 9200 floats

    proj_loc_kernel<<<(LOCN + PROWS - 1) / PROWS, 320, 0, stream>>>(
        emb_loc, W_ih, W_xt, W_xs, b, b_t, b_s, P);
    proj_ts_kernel<<<(2 * 92 * H_ + 255) / 256, 256, 0, stream>>>(
        emb_t, emb_s, W_tt, W_ss, P_t, P_s);
    lstm_rec_kernel<<<B_ / RB, NT, 0, stream>>>(
        traj, traj_len, tu, tl, tu_slot, tl_slot, su, sl, su_slot, sl_slot,
        P, P_t, P_s, W_hh, (float*)d_out);
}